// Round 3
// baseline (1050.699 us; speedup 1.0000x reference)
//
#include <hip/hip_runtime.h>
#include <hip/hip_cooperative_groups.h>
#include <hip/hip_bf16.h>
#include <math.h>

namespace cg = cooperative_groups;

#define NROWS 200704
#define DIM 512
#define NKM 32

// ---- workspace layout (offsets in 4-byte units) ----
#define OFF_RED0   0        // float[32]
#define OFF_RED1   32       // float[32]
#define OFF_RED2   64       // float[32]
#define OFF_CNT    96       // int[4]   rows per class
#define OFF_NP     100      // int[32]  per-prototype correct counts
#define OFF_CUR    192      // int[32*64] padded scatter cursors
#define OFF_BASE   2240     // int[32]  (unused now, kept for layout stability)
#define OFF_FACC   2304     // float[32*512] f accumulators
#define ZERO_FLOATS 18688   // memset range: everything above
#define OFF_SUMGP  18688    // float[32] sum_d g*pn
#define OFF_BP     18720    // float[32] sum_d b*pn
#define OFF_SCAL   18752    // float[3]: sum g^2, sum g*b, sum b^2
#define OFF_G2GB   18816    // float2[512]: (g^2, g*b) per dim
#define OFF_PROTON 19840    // float[32][512] normalized protos
#define OFF_WHI    36224    // ushort[32][520] bf16 hi plane of g*pn (8320 floats)
#define OFF_WLO    44544    // ushort[32][520] bf16 lo plane (8320 floats)
#define OFF_RSTATS 52864    // float4[N]: mu, istd, invL, 0
#define OFF_E      855680   // float[N][8]: exp(score/eps) for gt class
#define OFF_FLAGS  2461312  // int[N]: gt|(correct?4:0)
#define OFF_SORT   2662016  // int[N]: rows sorted by slot

typedef __attribute__((ext_vector_type(8)))  short short8;
typedef __attribute__((ext_vector_type(16))) float f32x16;

union ABFrag { unsigned int u[4]; short8 s; };

__device__ __forceinline__ unsigned int pk2(float a, float b) {
    // pack 2 floats to 2 bf16 (RNE), a in low 16 bits
    __hip_bfloat162 h2 = __float22bfloat162_rn(make_float2(a, b));
    union { __hip_bfloat162 h; unsigned int u; } cv;
    cv.h = h2;
    return cv.u;
}

__device__ __forceinline__ float block_reduce_sum(float v, float* sm) {
    int t = threadIdx.x;
    sm[t] = v; __syncthreads();
    #pragma unroll
    for (int o = 128; o > 0; o >>= 1) {
        if (t < o) sm[t] += sm[t + o];
        __syncthreads();
    }
    float r = sm[0]; __syncthreads();
    return r;
}

// ---- K0: normalize prototypes, build tables (fp32 + bf16 hi/lo planes) ----
__global__ __launch_bounds__(256) void k_prep(const float* __restrict__ protos,
                                              const float* __restrict__ g,
                                              const float* __restrict__ b,
                                              float* __restrict__ ws) {
    __shared__ float sm[256];
    int t = threadIdx.x, j = blockIdx.x;
    if (j < NKM) {
        const float* p = protos + j * DIM;
        float v = p[t] * p[t] + p[t + 256] * p[t + 256];
        float ss = block_reduce_sum(v, sm);
        float den = fmaxf(sqrtf(ss), 1e-12f);
        float sgp = 0.f, sbp = 0.f;
        unsigned short* whi = (unsigned short*)ws + 2 * OFF_WHI + j * 520;
        unsigned short* wlo = (unsigned short*)ws + 2 * OFF_WLO + j * 520;
        for (int d = t; d < DIM; d += 256) {
            float pn = p[d] / den;
            ws[OFF_PROTON + j * DIM + d] = pn;
            float w = g[d] * pn;
            unsigned int hb = pk2(w, 0.f) & 0xffffu;
            float hf = __uint_as_float(hb << 16);
            unsigned int lb = pk2(w - hf, 0.f) & 0xffffu;
            whi[d] = (unsigned short)hb;
            wlo[d] = (unsigned short)lb;
            sgp += w; sbp += b[d] * pn;
        }
        float s1 = block_reduce_sum(sgp, sm);
        float s2 = block_reduce_sum(sbp, sm);
        if (t == 0) { ws[OFF_SUMGP + j] = s1; ws[OFF_BP + j] = s2; }
    } else {
        float a = 0.f, c = 0.f, e = 0.f;
        for (int d = t; d < DIM; d += 256) {
            float gv = g[d], bv = b[d];
            ws[OFF_G2GB + 2 * d]     = gv * gv;
            ws[OFF_G2GB + 2 * d + 1] = gv * bv;
            a += gv * gv; c += gv * bv; e += bv * bv;
        }
        float s1 = block_reduce_sum(a, sm);
        float s2 = block_reduce_sum(c, sm);
        float s3 = block_reduce_sum(e, sm);
        if (t == 0) { ws[OFF_SCAL] = s1; ws[OFF_SCAL + 1] = s2; ws[OFF_SCAL + 2] = s3; }
    }
}

// ---- K1: fused LN + L2 + 32 dots via split-bf16 MFMA + fused red0. (unchanged) ----
#define ST1(XV, G2V, GBV) { float _x = (XV); float _x2 = _x * _x; \
    sx += _x; sxx += _x2; \
    sxg2  = fmaf(_x,  (G2V), sxg2); \
    sx2g2 = fmaf(_x2, (G2V), sx2g2); \
    sxgb  = fmaf(_x,  (GBV), sxgb); }

#define PAIRSPLIT(A0, B0, HO, LO) { \
    unsigned int _h = pk2((A0), (B0)); HO = _h; \
    float _ha = __uint_as_float(_h << 16); \
    float _hb = __uint_as_float(_h & 0xffff0000u); \
    LO = pk2((A0) - _ha, (B0) - _hb); }

__global__ __launch_bounds__(1024, 4) void k_main(const float* __restrict__ feats,
                                                  const float* __restrict__ mg,
                                                  const float* __restrict__ mb,
                                                  const int* __restrict__ gt_seg,
                                                  float* __restrict__ ws,
                                                  float* __restrict__ out) {
    __shared__ __align__(16) unsigned short ls_whi[32 * 520];
    __shared__ __align__(16) unsigned short ls_wlo[32 * 520];
    __shared__ __align__(16) float ls_g2gb[1024];
    __shared__ float s_lred[NKM];
    __shared__ int s_lcnt[4];
    int t = threadIdx.x;
    {
        const float4* sh = (const float4*)(ws + OFF_WHI);
        float4* dh = (float4*)ls_whi;
        for (int i = t; i < 2080; i += 1024) dh[i] = sh[i];
        const float4* sl = (const float4*)(ws + OFF_WLO);
        float4* dl = (float4*)ls_wlo;
        for (int i = t; i < 2080; i += 1024) dl[i] = sl[i];
        if (t < 256) ((float4*)ls_g2gb)[t] = ((const float4*)(ws + OFF_G2GB))[t];
        if (t < NKM) s_lred[t] = 0.f;
        if (t < 4) s_lcnt[t] = 0;
    }
    __syncthreads();

    int wv = t >> 6, l = t & 63;
    int h = l >> 5, c32 = l & 31;
    int row0 = blockIdx.x * 512 + wv * 32;
    const float* xrow = feats + (size_t)(row0 + c32) * DIM + h * 8;
    const unsigned short* bhp = ls_whi + c32 * 520 + h * 8;
    const unsigned short* blp = ls_wlo + c32 * 520 + h * 8;
    const float4* g4 = ((const float4*)ls_g2gb) + h * 4;

    f32x16 acc;
    #pragma unroll
    for (int i = 0; i < 16; ++i) acc[i] = 0.f;
    float sx = 0.f, sxx = 0.f, sxg2 = 0.f, sx2g2 = 0.f, sxgb = 0.f;

    #pragma unroll 2
    for (int kc = 0; kc < 32; ++kc) {
        float4 xa = *(const float4*)(xrow + kc * 16);
        float4 xb = *(const float4*)(xrow + kc * 16 + 4);
        float4 ga  = g4[kc * 8 + 0];
        float4 gb_ = g4[kc * 8 + 1];
        float4 gc  = g4[kc * 8 + 2];
        float4 gd  = g4[kc * 8 + 3];
        ST1(xa.x, ga.x,  ga.y)  ST1(xa.y, ga.z,  ga.w)
        ST1(xa.z, gb_.x, gb_.y) ST1(xa.w, gb_.z, gb_.w)
        ST1(xb.x, gc.x,  gc.y)  ST1(xb.y, gc.z,  gc.w)
        ST1(xb.z, gd.x,  gd.y)  ST1(xb.w, gd.z,  gd.w)
        ABFrag ah, al;
        PAIRSPLIT(xa.x, xa.y, ah.u[0], al.u[0])
        PAIRSPLIT(xa.z, xa.w, ah.u[1], al.u[1])
        PAIRSPLIT(xb.x, xb.y, ah.u[2], al.u[2])
        PAIRSPLIT(xb.z, xb.w, ah.u[3], al.u[3])
        short8 bh = *(const short8*)(bhp + kc * 16);
        short8 bl = *(const short8*)(blp + kc * 16);
        acc = __builtin_amdgcn_mfma_f32_32x32x16_bf16(ah.s, bh, acc, 0, 0, 0);
        acc = __builtin_amdgcn_mfma_f32_32x32x16_bf16(ah.s, bl, acc, 0, 0, 0);
        acc = __builtin_amdgcn_mfma_f32_32x32x16_bf16(al.s, bh, acc, 0, 0, 0);
    }

    sx    += __shfl_xor(sx, 32, 64);
    sxx   += __shfl_xor(sxx, 32, 64);
    sxg2  += __shfl_xor(sxg2, 32, 64);
    sx2g2 += __shfl_xor(sx2g2, 32, 64);
    sxgb  += __shfl_xor(sxgb, 32, 64);

    float scal0 = ws[OFF_SCAL], scal1 = ws[OFF_SCAL + 1], scal2 = ws[OFF_SCAL + 2];
    float mu  = sx * (1.0f / DIM);
    float var = sxx * (1.0f / DIM) - mu * mu;
    float istd = 1.0f / sqrtf(var + 1e-5f);
    float l2v = istd * istd * (sx2g2 - 2.0f * mu * sxg2 + mu * mu * scal0)
              + 2.0f * istd * (sxgb - mu * scal1) + scal2;
    float L = sqrtf(fmaxf(l2v, 0.0f));
    float invL = 1.0f / fmaxf(L, 1e-12f);
    float aa = istd * invL;
    if (l < 32)
        *(float4*)(ws + OFF_RSTATS + (size_t)(row0 + l) * 4) = make_float4(mu, istd, invL, 0.f);

    float wsum = ws[OFF_SUMGP + c32], wbp = ws[OFF_BP + c32];
    float mg0 = mg[0], mg1 = mg[1], mg2 = mg[2], mg3 = mg[3];
    float mb0 = mb[0], mb1 = mb[1], mb2 = mb[2], mb3 = mb[3];
    int q = c32 >> 3;      // own class
    int li8 = c32 & 7;     // proto within class

    #pragma unroll
    for (int r = 0; r < 16; ++r) {
        int rowt = (r & 3) + 8 * (r >> 2) + 4 * h;
        int grow = row0 + rowt;
        float mu_r = __shfl(mu, rowt, 64);
        float aa_r = __shfl(aa, rowt, 64);
        float il_r = __shfl(invL, rowt, 64);
        float s = aa_r * (acc[r] - mu_r * wsum) + il_r * wbp;
        float m = s;
        m = fmaxf(m, __shfl_xor(m, 1, 64));
        m = fmaxf(m, __shfl_xor(m, 2, 64));
        m = fmaxf(m, __shfl_xor(m, 4, 64));
        float vA = m;
        float vB = __shfl_xor(vA, 8, 64);
        float vC = __shfl_xor(vA, 16, 64);
        float vD = __shfl_xor(vB, 16, 64);
        float o0 = (q == 0) ? vA : (q == 1) ? vB : (q == 2) ? vC : vD;
        float o1 = (q == 1) ? vA : (q == 0) ? vB : (q == 3) ? vC : vD;
        float o2 = (q == 2) ? vA : (q == 3) ? vB : (q == 0) ? vC : vD;
        float o3 = (q == 3) ? vA : (q == 2) ? vB : (q == 1) ? vC : vD;
        float mu4 = 0.25f * (o0 + o1 + o2 + o3);
        float e0 = o0 - mu4, e1 = o1 - mu4, e2 = o2 - mu4, e3 = o3 - mu4;
        float v4 = 0.25f * (e0 * e0 + e1 * e1 + e2 * e2 + e3 * e3);
        float is4 = 1.0f / sqrtf(v4 + 1e-5f);
        float f0 = e0 * is4 * mg0 + mb0;
        float f1 = e1 * is4 * mg1 + mb1;
        float f2 = e2 * is4 * mg2 + mb2;
        float f3 = e3 * is4 * mg3 + mb3;
        int pred = 0; float bo = f0;
        if (f1 > bo) { bo = f1; pred = 1; }
        if (f2 > bo) { bo = f2; pred = 2; }
        if (f3 > bo) { bo = f3; pred = 3; }
        int gtv = gt_seg[grow] & 3;
        if (c32 == 0) {
            *(float4*)(out + (size_t)grow * 4) = make_float4(f0, f1, f2, f3);
            ((int*)ws)[OFF_FLAGS + grow] = gtv | ((pred == gtv) ? 4 : 0);
        }
        if (q == gtv) {
            float ev = expf(s * 20.0f);
            ws[OFF_E + (size_t)grow * 8 + li8] = ev;
            atomicAdd(&s_lred[(q << 3) + li8], ev);
            if (li8 == 0) atomicAdd(&s_lcnt[q], 1);
        }
    }
    __syncthreads();
    if (t < NKM) atomicAdd(&ws[OFF_RED0 + t], s_lred[t]);
    if (t < 4) atomicAdd(&((int*)ws)[OFF_CNT + t], s_lcnt[t]);
}

// ---- K2: the entire tail as ONE cooperative kernel.
// 784 blocks x 256 threads; each thread owns one row; ev[8]/flag/slot stay in
// registers across grid syncs. Phases: sinkhorn2 -> sinkhorn3 -> assign ->
// scatter -> aggregate (768 chunk-blocks) -> final EMA (32 blocks).
__global__ __launch_bounds__(256, 4) void k_sink(const float* __restrict__ feats,
                                                 const float* __restrict__ g,
                                                 const float* __restrict__ b,
                                                 const int* __restrict__ gt_seg,
                                                 float* __restrict__ ws,
                                                 float* __restrict__ out) {
    cg::grid_group grid = cg::this_grid();
    __shared__ float S0p[4], Bk[4], a1[NKM], a2[NKM], F[NKM], lred[NKM];
    __shared__ int ln[NKM], s_np[NKM], s_base[NKM];
    __shared__ float sm[256];
    int t = threadIdx.x;
    int row = blockIdx.x * 256 + t;
    int gt = gt_seg[row] & 3;
    float4 ea = *(const float4*)(ws + OFF_E + (size_t)row * 8);
    float4 eb = *(const float4*)(ws + OFF_E + (size_t)row * 8 + 4);
    float ev[8] = {ea.x, ea.y, ea.z, ea.w, eb.x, eb.y, eb.z, eb.w};
    int flag = ((const int*)ws)[OFF_FLAGS + row];

    // ---- phase A: sinkhorn iter-2 column sums (RED0/CNT ready from k_main)
    if (t < 4) {
        float s = 0.f;
        #pragma unroll
        for (int m = 0; m < 8; ++m) s += ws[OFF_RED0 + t * 8 + m];
        S0p[t] = fmaxf(s, 1e-30f);
        Bk[t] = fmaxf((float)((const int*)ws)[OFF_CNT + t], 1.0f);
    }
    if (t < NKM) lred[t] = 0.f;
    __syncthreads();
    if (t < NKM) {
        float col = ws[OFF_RED0 + t] / S0p[t >> 3];
        a1[t] = 1.0f / (fmaxf(col, 1e-30f) * 8.0f);
    }
    __syncthreads();
    float dotv = 0.f;
    #pragma unroll
    for (int m = 0; m < 8; ++m) dotv += ev[m] * a1[gt * 8 + m];
    float row1 = dotv / S0p[gt];
    float r1 = 1.0f / (fmaxf(row1, 1e-30f) * Bk[gt]);
    #pragma unroll
    for (int m = 0; m < 8; ++m) atomicAdd(&lred[gt * 8 + m], ev[m] * r1);
    __syncthreads();
    if (t < NKM) atomicAdd(&ws[OFF_RED1 + t], lred[t]);
    grid.sync();

    // ---- phase B: sinkhorn iter-3 column sums (RED1 complete)
    if (t < NKM) lred[t] = 0.f;
    __syncthreads();
    if (t < NKM) {
        float col2 = a1[t] * ws[OFF_RED1 + t] / S0p[t >> 3];
        a2[t] = 1.0f / (fmaxf(col2, 1e-30f) * 8.0f);
    }
    __syncthreads();
    float dot2 = 0.f;
    #pragma unroll
    for (int m = 0; m < 8; ++m) dot2 += ev[m] * a1[gt * 8 + m] * a2[gt * 8 + m];
    float row2 = dot2 / S0p[gt] * r1;
    float r2 = 1.0f / (fmaxf(row2, 1e-30f) * Bk[gt]);
    #pragma unroll
    for (int m = 0; m < 8; ++m) atomicAdd(&lred[gt * 8 + m], ev[m] * r1 * r2);
    __syncthreads();
    if (t < NKM) atomicAdd(&ws[OFF_RED2 + t], lred[t]);
    grid.sync();

    // ---- phase C: assignment argmax (RED2 complete)
    if (t < NKM) ln[t] = 0;
    __syncthreads();
    if (t < NKM) {
        float col3 = a1[t] * a2[t] * ws[OFF_RED2 + t] / S0p[t >> 3];
        float a3 = 1.0f / (fmaxf(col3, 1e-30f) * 8.0f);
        F[t] = a1[t] * a2[t] * a3;
    }
    __syncthreads();
    int slotv = -1;
    if (flag & 4) {
        int js = 0; float bv = ev[0] * F[gt * 8];
        #pragma unroll
        for (int m = 1; m < 8; ++m) {
            float v = ev[m] * F[gt * 8 + m];
            if (v > bv) { bv = v; js = m; }
        }
        slotv = gt * 8 + js;
        atomicAdd(&ln[slotv], 1);
    }
    __syncthreads();
    if (t < NKM && ln[t]) atomicAdd(&((int*)ws)[OFF_NP + t], ln[t]);
    grid.sync();

    // ---- phase D: scatter into slot-sorted list (NP complete)
    if (t < NKM) s_np[t] = ((const int*)ws)[OFF_NP + t];
    __syncthreads();
    if (t == 0) {
        int acc = 0;
        #pragma unroll
        for (int s2 = 0; s2 < NKM; ++s2) { s_base[s2] = acc; acc += s_np[s2]; }
    }
    __syncthreads();
    if (slotv >= 0) {
        int pos = atomicAdd(&((int*)ws)[OFF_CUR + slotv * 64], 1);
        ((int*)ws)[OFF_SORT + s_base[slotv] + pos] = row;
    }
    grid.sync();

    // ---- phase E: aggregate _c over sorted slot lists (768 chunk-blocks)
    if (blockIdx.x < NKM * 24) {
        int slot = blockIdx.x / 24, ch = blockIdx.x % 24;
        int n = s_np[slot], base = s_base[slot];
        int r0 = base + (ch * n) / 24;
        int r1e = base + ((ch + 1) * n) / 24;
        if (r0 < r1e) {
            const int* sortl = (const int*)ws + OFF_SORT;
            float2 gv = *(const float2*)(g + 2 * t);
            float2 bv = *(const float2*)(b + 2 * t);
            float acc0 = 0.f, acc1 = 0.f;
            #pragma unroll 4
            for (int i = r0; i < r1e; ++i) {
                int rr = sortl[i];
                float4 rs = *(const float4*)(ws + OFF_RSTATS + (size_t)rr * 4); // mu,istd,invL
                float2 x = *(const float2*)(feats + (size_t)rr * DIM + 2 * t);
                acc0 += ((x.x - rs.x) * rs.y * gv.x + bv.x) * rs.z;
                acc1 += ((x.y - rs.x) * rs.y * gv.y + bv.y) * rs.z;
            }
            atomicAdd(&ws[OFF_FACC + slot * DIM + 2 * t],     acc0);
            atomicAdd(&ws[OFF_FACC + slot * DIM + 2 * t + 1], acc1);
        }
    }
    grid.sync();

    // ---- phase F: l2-normalize f, EMA update, final renormalize (32 blocks)
    if (blockIdx.x < NKM) {
        int j = blockIdx.x, k = j >> 3;
        int nj = s_np[j];
        int ck = ((const int*)ws)[OFF_CNT + k];
        int nsum = 0;
        #pragma unroll
        for (int m = 0; m < 8; ++m) nsum += s_np[k * 8 + m];
        int d0 = t, d1 = t + 256;
        float f0 = ws[OFF_FACC + j * DIM + d0];
        float f1 = ws[OFF_FACC + j * DIM + d1];
        float nf = block_reduce_sum(f0 * f0 + f1 * f1, sm);
        float fin = 1.0f / fmaxf(sqrtf(nf), 1e-12f);
        float pn0 = ws[OFF_PROTON + j * DIM + d0];
        float pn1 = ws[OFF_PROTON + j * DIM + d1];
        bool valid = (nj != 0) && (ck > 0) && (nsum > 0);
        float rr0 = valid ? (0.999f * pn0 + 0.001f * (f0 * fin)) : pn0;
        float rr1 = valid ? (0.999f * pn1 + 0.001f * (f1 * fin)) : pn1;
        float n2 = block_reduce_sum(rr0 * rr0 + rr1 * rr1, sm);
        float i2 = 1.0f / fmaxf(sqrtf(n2), 1e-12f);
        out[(size_t)NROWS * 4 + j * DIM + d0] = rr0 * i2;
        out[(size_t)NROWS * 4 + j * DIM + d1] = rr1 * i2;
    }
}

extern "C" void kernel_launch(void* const* d_in, const int* in_sizes, int n_in,
                              void* d_out, int out_size, void* d_ws, size_t ws_size,
                              hipStream_t stream) {
    const float* feats = (const float*)d_in[0];
    const float* ln_g  = (const float*)d_in[1];
    const float* ln_b  = (const float*)d_in[2];
    const float* mg    = (const float*)d_in[3];
    const float* mb    = (const float*)d_in[4];
    const float* prot  = (const float*)d_in[5];
    const int*   gt    = (const int*)d_in[6];
    float* out = (float*)d_out;
    float* ws  = (float*)d_ws;

    hipMemsetAsync(d_ws, 0, ZERO_FLOATS * 4, stream);
    k_prep<<<33, 256, 0, stream>>>(prot, ln_g, ln_b, ws);
    k_main<<<NROWS / 512, 1024, 0, stream>>>(feats, mg, mb, gt, ws, out);
    void* args[] = { (void*)&feats, (void*)&ln_g, (void*)&ln_b,
                     (void*)&gt, (void*)&ws, (void*)&out };
    hipLaunchCooperativeKernel(reinterpret_cast<void*>(k_sink),
                               dim3(NROWS / 256), dim3(256), args, 0, stream);
}

// Round 4
// 670.592 us; speedup vs baseline: 1.5668x; 1.5668x over previous
//
#include <hip/hip_runtime.h>
#include <hip/hip_bf16.h>
#include <math.h>

#define NROWS 200704
#define DIM 512
#define NKM 32

// ---- workspace layout (offsets in 4-byte units) ----
#define OFF_RED0   0        // float[32]
#define OFF_RED1   32       // float[32]
#define OFF_RED2   64       // float[32]
#define OFF_CNT    96       // int[4]   rows per class
#define OFF_NP     100      // int[32]  (unused; CUR doubles as count now)
#define OFF_CUR    192      // int[32*64] padded scatter cursors (= per-slot counts)
#define OFF_BASE   2240     // int[32]  (unused, layout stability)
#define OFF_FACC   2304     // float[32*512] f accumulators
#define ZERO_FLOATS 18688   // memset range: everything above
#define OFF_SUMGP  18688    // float[32] sum_d g*pn
#define OFF_BP     18720    // float[32] sum_d b*pn
#define OFF_SCAL   18752    // float[3]: sum g^2, sum g*b, sum b^2
#define OFF_G2GB   18816    // float2[512]: (g^2, g*b) per dim
#define OFF_PROTON 19840    // float[32][512] normalized protos
#define OFF_WHI    36224    // ushort[32][520] bf16 hi plane of g*pn (8320 floats)
#define OFF_WLO    44544    // ushort[32][520] bf16 lo plane (8320 floats)
#define OFF_RSTATS 52864    // float4[N]: mu, istd, invL, 0
#define OFF_E      855680   // float[N][8]: exp(score/eps) for gt class
#define OFF_FLAGS  2461312  // int[N]: gt|(correct?4:0)
#define OFF_BUCKET 4000000  // int[32][N]: per-slot row buckets (no zeroing needed)

typedef __attribute__((ext_vector_type(8)))  short short8;
typedef __attribute__((ext_vector_type(16))) float f32x16;

union ABFrag { unsigned int u[4]; short8 s; };

__device__ __forceinline__ unsigned int pk2(float a, float b) {
    // pack 2 floats to 2 bf16 (RNE), a in low 16 bits
    __hip_bfloat162 h2 = __float22bfloat162_rn(make_float2(a, b));
    union { __hip_bfloat162 h; unsigned int u; } cv;
    cv.h = h2;
    return cv.u;
}

__device__ __forceinline__ float block_reduce_sum(float v, float* sm) {
    int t = threadIdx.x;
    sm[t] = v; __syncthreads();
    #pragma unroll
    for (int o = 128; o > 0; o >>= 1) {
        if (t < o) sm[t] += sm[t + o];
        __syncthreads();
    }
    float r = sm[0]; __syncthreads();
    return r;
}

// ---- K0: normalize prototypes, build tables (fp32 + bf16 hi/lo planes) ----
__global__ __launch_bounds__(256) void k_prep(const float* __restrict__ protos,
                                              const float* __restrict__ g,
                                              const float* __restrict__ b,
                                              float* __restrict__ ws) {
    __shared__ float sm[256];
    int t = threadIdx.x, j = blockIdx.x;
    if (j < NKM) {
        const float* p = protos + j * DIM;
        float v = p[t] * p[t] + p[t + 256] * p[t + 256];
        float ss = block_reduce_sum(v, sm);
        float den = fmaxf(sqrtf(ss), 1e-12f);
        float sgp = 0.f, sbp = 0.f;
        unsigned short* whi = (unsigned short*)ws + 2 * OFF_WHI + j * 520;
        unsigned short* wlo = (unsigned short*)ws + 2 * OFF_WLO + j * 520;
        for (int d = t; d < DIM; d += 256) {
            float pn = p[d] / den;
            ws[OFF_PROTON + j * DIM + d] = pn;
            float w = g[d] * pn;
            unsigned int hb = pk2(w, 0.f) & 0xffffu;
            float hf = __uint_as_float(hb << 16);
            unsigned int lb = pk2(w - hf, 0.f) & 0xffffu;
            whi[d] = (unsigned short)hb;
            wlo[d] = (unsigned short)lb;
            sgp += w; sbp += b[d] * pn;
        }
        float s1 = block_reduce_sum(sgp, sm);
        float s2 = block_reduce_sum(sbp, sm);
        if (t == 0) { ws[OFF_SUMGP + j] = s1; ws[OFF_BP + j] = s2; }
    } else {
        float a = 0.f, c = 0.f, e = 0.f;
        for (int d = t; d < DIM; d += 256) {
            float gv = g[d], bv = b[d];
            ws[OFF_G2GB + 2 * d]     = gv * gv;
            ws[OFF_G2GB + 2 * d + 1] = gv * bv;
            a += gv * gv; c += gv * bv; e += bv * bv;
        }
        float s1 = block_reduce_sum(a, sm);
        float s2 = block_reduce_sum(c, sm);
        float s3 = block_reduce_sum(e, sm);
        if (t == 0) { ws[OFF_SCAL] = s1; ws[OFF_SCAL + 1] = s2; ws[OFF_SCAL + 2] = s3; }
    }
}

// ---- K1: fused LN + L2 + 32 dots via split-bf16 MFMA + fused red0. ----
#define ST1(XV, G2V, GBV) { float _x = (XV); float _x2 = _x * _x; \
    sx += _x; sxx += _x2; \
    sxg2  = fmaf(_x,  (G2V), sxg2); \
    sx2g2 = fmaf(_x2, (G2V), sx2g2); \
    sxgb  = fmaf(_x,  (GBV), sxgb); }

#define PAIRSPLIT(A0, B0, HO, LO) { \
    unsigned int _h = pk2((A0), (B0)); HO = _h; \
    float _ha = __uint_as_float(_h << 16); \
    float _hb = __uint_as_float(_h & 0xffff0000u); \
    LO = pk2((A0) - _ha, (B0) - _hb); }

__global__ __launch_bounds__(1024, 4) void k_main(const float* __restrict__ feats,
                                                  const float* __restrict__ mg,
                                                  const float* __restrict__ mb,
                                                  const int* __restrict__ gt_seg,
                                                  float* __restrict__ ws,
                                                  float* __restrict__ out) {
    __shared__ __align__(16) unsigned short ls_whi[32 * 520];
    __shared__ __align__(16) unsigned short ls_wlo[32 * 520];
    __shared__ __align__(16) float ls_g2gb[1024];
    __shared__ float s_lred[NKM];
    __shared__ int s_lcnt[4];
    int t = threadIdx.x;
    {
        const float4* sh = (const float4*)(ws + OFF_WHI);
        float4* dh = (float4*)ls_whi;
        for (int i = t; i < 2080; i += 1024) dh[i] = sh[i];
        const float4* sl = (const float4*)(ws + OFF_WLO);
        float4* dl = (float4*)ls_wlo;
        for (int i = t; i < 2080; i += 1024) dl[i] = sl[i];
        if (t < 256) ((float4*)ls_g2gb)[t] = ((const float4*)(ws + OFF_G2GB))[t];
        if (t < NKM) s_lred[t] = 0.f;
        if (t < 4) s_lcnt[t] = 0;
    }
    __syncthreads();

    int wv = t >> 6, l = t & 63;
    int h = l >> 5, c32 = l & 31;
    int row0 = blockIdx.x * 512 + wv * 32;
    const float* xrow = feats + (size_t)(row0 + c32) * DIM + h * 8;
    const unsigned short* bhp = ls_whi + c32 * 520 + h * 8;
    const unsigned short* blp = ls_wlo + c32 * 520 + h * 8;
    const float4* g4 = ((const float4*)ls_g2gb) + h * 4;

    f32x16 acc;
    #pragma unroll
    for (int i = 0; i < 16; ++i) acc[i] = 0.f;
    float sx = 0.f, sxx = 0.f, sxg2 = 0.f, sx2g2 = 0.f, sxgb = 0.f;

    #pragma unroll 2
    for (int kc = 0; kc < 32; ++kc) {
        float4 xa = *(const float4*)(xrow + kc * 16);
        float4 xb = *(const float4*)(xrow + kc * 16 + 4);
        float4 ga  = g4[kc * 8 + 0];
        float4 gb_ = g4[kc * 8 + 1];
        float4 gc  = g4[kc * 8 + 2];
        float4 gd  = g4[kc * 8 + 3];
        ST1(xa.x, ga.x,  ga.y)  ST1(xa.y, ga.z,  ga.w)
        ST1(xa.z, gb_.x, gb_.y) ST1(xa.w, gb_.z, gb_.w)
        ST1(xb.x, gc.x,  gc.y)  ST1(xb.y, gc.z,  gc.w)
        ST1(xb.z, gd.x,  gd.y)  ST1(xb.w, gd.z,  gd.w)
        ABFrag ah, al;
        PAIRSPLIT(xa.x, xa.y, ah.u[0], al.u[0])
        PAIRSPLIT(xa.z, xa.w, ah.u[1], al.u[1])
        PAIRSPLIT(xb.x, xb.y, ah.u[2], al.u[2])
        PAIRSPLIT(xb.z, xb.w, ah.u[3], al.u[3])
        short8 bh = *(const short8*)(bhp + kc * 16);
        short8 bl = *(const short8*)(blp + kc * 16);
        acc = __builtin_amdgcn_mfma_f32_32x32x16_bf16(ah.s, bh, acc, 0, 0, 0);
        acc = __builtin_amdgcn_mfma_f32_32x32x16_bf16(ah.s, bl, acc, 0, 0, 0);
        acc = __builtin_amdgcn_mfma_f32_32x32x16_bf16(al.s, bh, acc, 0, 0, 0);
    }

    sx    += __shfl_xor(sx, 32, 64);
    sxx   += __shfl_xor(sxx, 32, 64);
    sxg2  += __shfl_xor(sxg2, 32, 64);
    sx2g2 += __shfl_xor(sx2g2, 32, 64);
    sxgb  += __shfl_xor(sxgb, 32, 64);

    float scal0 = ws[OFF_SCAL], scal1 = ws[OFF_SCAL + 1], scal2 = ws[OFF_SCAL + 2];
    float mu  = sx * (1.0f / DIM);
    float var = sxx * (1.0f / DIM) - mu * mu;
    float istd = 1.0f / sqrtf(var + 1e-5f);
    float l2v = istd * istd * (sx2g2 - 2.0f * mu * sxg2 + mu * mu * scal0)
              + 2.0f * istd * (sxgb - mu * scal1) + scal2;
    float L = sqrtf(fmaxf(l2v, 0.0f));
    float invL = 1.0f / fmaxf(L, 1e-12f);
    float aa = istd * invL;
    if (l < 32)
        *(float4*)(ws + OFF_RSTATS + (size_t)(row0 + l) * 4) = make_float4(mu, istd, invL, 0.f);

    float wsum = ws[OFF_SUMGP + c32], wbp = ws[OFF_BP + c32];
    float mg0 = mg[0], mg1 = mg[1], mg2 = mg[2], mg3 = mg[3];
    float mb0 = mb[0], mb1 = mb[1], mb2 = mb[2], mb3 = mb[3];
    int q = c32 >> 3;      // own class
    int li8 = c32 & 7;     // proto within class

    #pragma unroll
    for (int r = 0; r < 16; ++r) {
        int rowt = (r & 3) + 8 * (r >> 2) + 4 * h;
        int grow = row0 + rowt;
        float mu_r = __shfl(mu, rowt, 64);
        float aa_r = __shfl(aa, rowt, 64);
        float il_r = __shfl(invL, rowt, 64);
        float s = aa_r * (acc[r] - mu_r * wsum) + il_r * wbp;
        float m = s;
        m = fmaxf(m, __shfl_xor(m, 1, 64));
        m = fmaxf(m, __shfl_xor(m, 2, 64));
        m = fmaxf(m, __shfl_xor(m, 4, 64));
        float vA = m;
        float vB = __shfl_xor(vA, 8, 64);
        float vC = __shfl_xor(vA, 16, 64);
        float vD = __shfl_xor(vB, 16, 64);
        float o0 = (q == 0) ? vA : (q == 1) ? vB : (q == 2) ? vC : vD;
        float o1 = (q == 1) ? vA : (q == 0) ? vB : (q == 3) ? vC : vD;
        float o2 = (q == 2) ? vA : (q == 3) ? vB : (q == 0) ? vC : vD;
        float o3 = (q == 3) ? vA : (q == 2) ? vB : (q == 1) ? vC : vD;
        float mu4 = 0.25f * (o0 + o1 + o2 + o3);
        float e0 = o0 - mu4, e1 = o1 - mu4, e2 = o2 - mu4, e3 = o3 - mu4;
        float v4 = 0.25f * (e0 * e0 + e1 * e1 + e2 * e2 + e3 * e3);
        float is4 = 1.0f / sqrtf(v4 + 1e-5f);
        float f0 = e0 * is4 * mg0 + mb0;
        float f1 = e1 * is4 * mg1 + mb1;
        float f2 = e2 * is4 * mg2 + mb2;
        float f3 = e3 * is4 * mg3 + mb3;
        int pred = 0; float bo = f0;
        if (f1 > bo) { bo = f1; pred = 1; }
        if (f2 > bo) { bo = f2; pred = 2; }
        if (f3 > bo) { bo = f3; pred = 3; }
        int gtv = gt_seg[grow] & 3;
        if (c32 == 0) {
            *(float4*)(out + (size_t)grow * 4) = make_float4(f0, f1, f2, f3);
            ((int*)ws)[OFF_FLAGS + grow] = gtv | ((pred == gtv) ? 4 : 0);
        }
        if (q == gtv) {
            float ev = expf(s * 20.0f);
            ws[OFF_E + (size_t)grow * 8 + li8] = ev;
            atomicAdd(&s_lred[(q << 3) + li8], ev);
            if (li8 == 0) atomicAdd(&s_lcnt[q], 1);
        }
    }
    __syncthreads();
    if (t < NKM) atomicAdd(&ws[OFF_RED0 + t], s_lred[t]);
    if (t < 4) atomicAdd(&((int*)ws)[OFF_CNT + t], s_lcnt[t]);
}

// ---- K2b: sinkhorn iteration-2 column sums. 196 blocks x 4 rows/thread. ----
__global__ __launch_bounds__(256) void k_red1(const int* __restrict__ gt_seg,
                                              float* __restrict__ ws) {
    __shared__ float S0p[4], Bk[4], a1[NKM], lred[NKM];
    int t = threadIdx.x;
    if (t < 4) {
        float s = 0.f;
        #pragma unroll
        for (int m = 0; m < 8; ++m) s += ws[OFF_RED0 + t * 8 + m];
        S0p[t] = fmaxf(s, 1e-30f);
        Bk[t] = fmaxf((float)((const int*)ws)[OFF_CNT + t], 1.0f);
    }
    if (t < NKM) lred[t] = 0.f;
    __syncthreads();
    if (t < NKM) {
        float col = ws[OFF_RED0 + t] / S0p[t >> 3];
        a1[t] = 1.0f / (fmaxf(col, 1e-30f) * 8.0f);
    }
    __syncthreads();
    #pragma unroll
    for (int i = 0; i < 4; ++i) {
        int row = blockIdx.x * 1024 + i * 256 + t;
        int gt = gt_seg[row] & 3;
        float4 ea = *(const float4*)(ws + OFF_E + (size_t)row * 8);
        float4 eb = *(const float4*)(ws + OFF_E + (size_t)row * 8 + 4);
        float ev[8] = {ea.x, ea.y, ea.z, ea.w, eb.x, eb.y, eb.z, eb.w};
        float dotv = 0.f;
        #pragma unroll
        for (int m = 0; m < 8; ++m) dotv += ev[m] * a1[gt * 8 + m];
        float row1 = dotv / S0p[gt];
        float r1 = 1.0f / (fmaxf(row1, 1e-30f) * Bk[gt]);
        #pragma unroll
        for (int m = 0; m < 8; ++m) atomicAdd(&lred[gt * 8 + m], ev[m] * r1);
    }
    __syncthreads();
    if (t < NKM) atomicAdd(&ws[OFF_RED1 + t], lred[t]);
}

// ---- K2c: sinkhorn iteration-3 column sums. 196 blocks x 4 rows/thread. ----
__global__ __launch_bounds__(256) void k_red2(const int* __restrict__ gt_seg,
                                              float* __restrict__ ws) {
    __shared__ float S0p[4], Bk[4], a1[NKM], a2[NKM], lred[NKM];
    int t = threadIdx.x;
    if (t < 4) {
        float s = 0.f;
        #pragma unroll
        for (int m = 0; m < 8; ++m) s += ws[OFF_RED0 + t * 8 + m];
        S0p[t] = fmaxf(s, 1e-30f);
        Bk[t] = fmaxf((float)((const int*)ws)[OFF_CNT + t], 1.0f);
    }
    if (t < NKM) lred[t] = 0.f;
    __syncthreads();
    if (t < NKM) {
        float col = ws[OFF_RED0 + t] / S0p[t >> 3];
        a1[t] = 1.0f / (fmaxf(col, 1e-30f) * 8.0f);
    }
    __syncthreads();
    if (t < NKM) {
        float col2 = a1[t] * ws[OFF_RED1 + t] / S0p[t >> 3];
        a2[t] = 1.0f / (fmaxf(col2, 1e-30f) * 8.0f);
    }
    __syncthreads();
    #pragma unroll
    for (int i = 0; i < 4; ++i) {
        int row = blockIdx.x * 1024 + i * 256 + t;
        int gt = gt_seg[row] & 3;
        float4 ea = *(const float4*)(ws + OFF_E + (size_t)row * 8);
        float4 eb = *(const float4*)(ws + OFF_E + (size_t)row * 8 + 4);
        float ev[8] = {ea.x, ea.y, ea.z, ea.w, eb.x, eb.y, eb.z, eb.w};
        float dotv = 0.f;
        #pragma unroll
        for (int m = 0; m < 8; ++m) dotv += ev[m] * a1[gt * 8 + m];
        float row1 = dotv / S0p[gt];
        float r1 = 1.0f / (fmaxf(row1, 1e-30f) * Bk[gt]);
        float dot2 = 0.f;
        #pragma unroll
        for (int m = 0; m < 8; ++m) dot2 += ev[m] * a1[gt * 8 + m] * a2[gt * 8 + m];
        float row2 = dot2 / S0p[gt] * r1;
        float r2 = 1.0f / (fmaxf(row2, 1e-30f) * Bk[gt]);
        #pragma unroll
        for (int m = 0; m < 8; ++m) atomicAdd(&lred[gt * 8 + m], ev[m] * r1 * r2);
    }
    __syncthreads();
    if (t < NKM) atomicAdd(&ws[OFF_RED2 + t], lred[t]);
}

// ---- K3: argmax assignment + direct bucket scatter (CUR = per-slot count) ----
__global__ __launch_bounds__(256) void k_assign(float* __restrict__ ws) {
    __shared__ float S0p[4], a1[NKM], a2[NKM], F[NKM];
    int t = threadIdx.x;
    if (t < 4) {
        float s = 0.f;
        #pragma unroll
        for (int m = 0; m < 8; ++m) s += ws[OFF_RED0 + t * 8 + m];
        S0p[t] = fmaxf(s, 1e-30f);
    }
    __syncthreads();
    if (t < NKM) {
        float col = ws[OFF_RED0 + t] / S0p[t >> 3];
        a1[t] = 1.0f / (fmaxf(col, 1e-30f) * 8.0f);
    }
    __syncthreads();
    if (t < NKM) {
        float col2 = a1[t] * ws[OFF_RED1 + t] / S0p[t >> 3];
        a2[t] = 1.0f / (fmaxf(col2, 1e-30f) * 8.0f);
    }
    __syncthreads();
    if (t < NKM) {
        float col3 = a1[t] * a2[t] * ws[OFF_RED2 + t] / S0p[t >> 3];
        float a3 = 1.0f / (fmaxf(col3, 1e-30f) * 8.0f);
        F[t] = a1[t] * a2[t] * a3;
    }
    __syncthreads();
    int row = blockIdx.x * 256 + t;
    int flag = ((const int*)ws)[OFF_FLAGS + row];
    if (flag & 4) {
        int gt = flag & 3;
        float4 ea = *(const float4*)(ws + OFF_E + (size_t)row * 8);
        float4 eb = *(const float4*)(ws + OFF_E + (size_t)row * 8 + 4);
        float ev[8] = {ea.x, ea.y, ea.z, ea.w, eb.x, eb.y, eb.z, eb.w};
        int js = 0; float bv = ev[0] * F[gt * 8];
        #pragma unroll
        for (int m = 1; m < 8; ++m) {
            float v = ev[m] * F[gt * 8 + m];
            if (v > bv) { bv = v; js = m; }
        }
        int slotv = gt * 8 + js;
        int pos = atomicAdd(&((int*)ws)[OFF_CUR + slotv * 64], 1);
        ((int*)ws)[OFF_BUCKET + (size_t)slotv * NROWS + pos] = row;
    }
}

// ---- K4: aggregate _c over per-slot buckets, register accumulation ----
__global__ __launch_bounds__(256) void k_agg(const float* __restrict__ feats,
                                             const float* __restrict__ g,
                                             const float* __restrict__ b,
                                             float* __restrict__ ws) {
    int t = threadIdx.x;
    int slot = blockIdx.x >> 4, ch = blockIdx.x & 15;
    int n = ((const int*)ws)[OFF_CUR + slot * 64];
    int r0 = (ch * n) / 16;
    int r1 = ((ch + 1) * n) / 16;
    if (r0 >= r1) return;
    const int* bucket = (const int*)ws + OFF_BUCKET + (size_t)slot * NROWS;
    float2 gv = *(const float2*)(g + 2 * t);
    float2 bv = *(const float2*)(b + 2 * t);
    float acc0 = 0.f, acc1 = 0.f;
    #pragma unroll 4
    for (int i = r0; i < r1; ++i) {
        int row = bucket[i];
        float4 rs = *(const float4*)(ws + OFF_RSTATS + (size_t)row * 4); // mu,istd,invL
        float2 x = *(const float2*)(feats + (size_t)row * DIM + 2 * t);
        acc0 += ((x.x - rs.x) * rs.y * gv.x + bv.x) * rs.z;
        acc1 += ((x.y - rs.x) * rs.y * gv.y + bv.y) * rs.z;
    }
    atomicAdd(&ws[OFF_FACC + slot * DIM + 2 * t],     acc0);
    atomicAdd(&ws[OFF_FACC + slot * DIM + 2 * t + 1], acc1);
}

// ---- K5: l2-normalize f, EMA update, final renormalize ----
__global__ __launch_bounds__(256) void k_final(float* __restrict__ ws,
                                               float* __restrict__ out) {
    __shared__ float sm[256];
    int t = threadIdx.x, j = blockIdx.x, k = j >> 3;
    int nj = ((const int*)ws)[OFF_CUR + j * 64];
    int ck = ((const int*)ws)[OFF_CNT + k];
    int nsum = 0;
    #pragma unroll
    for (int m = 0; m < 8; ++m) nsum += ((const int*)ws)[OFF_CUR + (k * 8 + m) * 64];
    int d0 = t, d1 = t + 256;
    float f0 = ws[OFF_FACC + j * DIM + d0];
    float f1 = ws[OFF_FACC + j * DIM + d1];
    float nf = block_reduce_sum(f0 * f0 + f1 * f1, sm);
    float fin = 1.0f / fmaxf(sqrtf(nf), 1e-12f);
    float pn0 = ws[OFF_PROTON + j * DIM + d0];
    float pn1 = ws[OFF_PROTON + j * DIM + d1];
    bool valid = (nj != 0) && (ck > 0) && (nsum > 0);
    float r0 = valid ? (0.999f * pn0 + 0.001f * (f0 * fin)) : pn0;
    float r1 = valid ? (0.999f * pn1 + 0.001f * (f1 * fin)) : pn1;
    float n2 = block_reduce_sum(r0 * r0 + r1 * r1, sm);
    float i2 = 1.0f / fmaxf(sqrtf(n2), 1e-12f);
    out[(size_t)NROWS * 4 + j * DIM + d0] = r0 * i2;
    out[(size_t)NROWS * 4 + j * DIM + d1] = r1 * i2;
}

extern "C" void kernel_launch(void* const* d_in, const int* in_sizes, int n_in,
                              void* d_out, int out_size, void* d_ws, size_t ws_size,
                              hipStream_t stream) {
    const float* feats = (const float*)d_in[0];
    const float* ln_g  = (const float*)d_in[1];
    const float* ln_b  = (const float*)d_in[2];
    const float* mg    = (const float*)d_in[3];
    const float* mb    = (const float*)d_in[4];
    const float* prot  = (const float*)d_in[5];
    const int*   gt    = (const int*)d_in[6];
    float* out = (float*)d_out;
    float* ws  = (float*)d_ws;

    hipMemsetAsync(d_ws, 0, ZERO_FLOATS * 4, stream);
    k_prep<<<33, 256, 0, stream>>>(prot, ln_g, ln_b, ws);
    k_main<<<NROWS / 512, 1024, 0, stream>>>(feats, mg, mb, gt, ws, out);
    k_red1<<<196, 256, 0, stream>>>(gt, ws);
    k_red2<<<196, 256, 0, stream>>>(gt, ws);
    k_assign<<<NROWS / 256, 256, 0, stream>>>(ws);
    k_agg<<<NKM * 16, 256, 0, stream>>>(feats, ln_g, ln_b, ws);
    k_final<<<NKM, 256, 0, stream>>>(ws, out);
}